// Round 3
// baseline (528.684 us; speedup 1.0000x reference)
//
#include <hip/hip_runtime.h>
#include <hip/hip_bf16.h>

#define B_ROWS 1024
#define V_DIM 50257
#define E_DIM 128
#define V_PAD 50304  // 786 * 64, >= V_DIM; GEMM tail tiles read zero-padding
#define NCT 786      // number of 64-wide col tiles
#define K0_BLOCKS (1572 * 4)  // transpose grid: (V_PAD/32) * (E_DIM/32)

typedef __attribute__((ext_vector_type(8))) short short8;
typedef __attribute__((ext_vector_type(4))) float float4v;

// ---------------------------------------------------------------------------
// kfuse: blocks [0,1024) do the xs-row scan + embed gather (k1);
//        blocks [1024, 1024+K0_BLOCKS) do the e2v transpose+cast (k0).
// Independent work, concurrent occupancy, one dispatch.
// ---------------------------------------------------------------------------
__global__ void kfuse(const float* __restrict__ xs,
                      const float* __restrict__ EM,
                      __hip_bfloat16* __restrict__ xse,
                      const float* __restrict__ e2v,
                      __hip_bfloat16* __restrict__ e2vT) {
    const int tid = threadIdx.x;
    if (blockIdx.x < B_ROWS) {
        // ---- k1: per-row nonzero scan + gather-accumulate ----
        const int b = blockIdx.x;
        __shared__ int nzv[64];
        __shared__ float nzval[64];
        __shared__ int nzcount;
        if (tid == 0) nzcount = 0;
        __syncthreads();

        const size_t base = (size_t)b * V_DIM;
        auto note = [&](int v, float val) {
            if (val != 0.0f) {
                int s = atomicAdd(&nzcount, 1);
                if (s < 64) { nzv[s] = v; nzval[s] = val; }
            }
        };

        const int h = (int)((4 - (base & 3)) & 3);
        if (tid < h) note(tid, xs[base + tid]);
        const int n4 = (V_DIM - h) >> 2;
        const float4* xv = reinterpret_cast<const float4*>(xs + base + h);
        for (int j = tid; j < n4; j += 256) {
            float4 x = xv[j];
            if (x.x != 0.0f || x.y != 0.0f || x.z != 0.0f || x.w != 0.0f) {
                const int v = h + 4 * j;
                note(v + 0, x.x);
                note(v + 1, x.y);
                note(v + 2, x.z);
                note(v + 3, x.w);
            }
        }
        for (int i = h + n4 * 4 + tid; i < V_DIM; i += 256) note(i, xs[base + i]);
        __syncthreads();

        int cnt = nzcount;
        if (cnt > 64) cnt = 64;
        if (tid < E_DIM) {
            float a = 0.0f;
            for (int s = 0; s < cnt; ++s)
                a += nzval[s] * EM[(size_t)nzv[s] * E_DIM + tid];
            xse[(size_t)b * E_DIM + tid] = __float2bfloat16(a);
        }
    } else {
        // ---- k0: transpose + cast e2v [E][V] fp32 -> e2vT [V_PAD][E] bf16 ----
        __shared__ float t[32][33];
        const int bx = blockIdx.x - B_ROWS;
        const int v0 = (bx % 1572) * 32;
        const int kk0 = (bx / 1572) * 32;
        const int c = tid & 31;
        const int r = tid >> 5;  // 0..7
#pragma unroll
        for (int i = 0; i < 4; ++i) {
            const int k = kk0 + r + i * 8;
            const int v = v0 + c;
            t[r + i * 8][c] = (v < V_DIM) ? e2v[(size_t)k * V_DIM + v] : 0.0f;
        }
        __syncthreads();
#pragma unroll
        for (int i = 0; i < 4; ++i) {
            const int rv = r + i * 8;
            e2vT[(size_t)(v0 + rv) * E_DIM + kk0 + c] = __float2bfloat16(t[c][rv]);
        }
    }
}

// ---------------------------------------------------------------------------
// LDS-free GEMM tile: block = 128 rows x 64 cols, K = 128 (full reduction).
// 4 waves, each 32 rows x 64 cols. All A/B MFMA fragments are 16B-aligned
// contiguous global chunks (K=128 row-major) -> direct int4 loads, no LDS,
// no __syncthreads. A: 8 int4/lane, B: 16 int4/lane (L2/L3-resident).
// Grid (NCT, 8): vt fastest -> B tile reuse across row-tiles in L2/L3.
// C/D layout (m89-verified): col = lane&15, row = (lane>>4)*4 + reg.
// ---------------------------------------------------------------------------
#define GEMM_REG_BODY(xse, e2vT)                                               \
    const int tid = threadIdx.x;                                               \
    const int vt = blockIdx.x;                                                 \
    const int m0 = blockIdx.y * 128;                                           \
    const int v0 = vt * 64;                                                    \
    const int w = tid >> 6;                                                    \
    const int lane = tid & 63;                                                 \
    const int q = lane >> 4;                                                   \
    const int l16 = lane & 15;                                                 \
    const int wm = w * 32;                                                     \
    const unsigned short* gA = reinterpret_cast<const unsigned short*>(xse);   \
    const unsigned short* gB = reinterpret_cast<const unsigned short*>(e2vT);  \
    short8 a[2][4];                                                            \
    _Pragma("unroll")                                                          \
    for (int mi = 0; mi < 2; ++mi) {                                           \
        const size_t rowa = (size_t)(m0 + wm + mi * 16 + l16) * E_DIM;         \
        _Pragma("unroll")                                                      \
        for (int kx = 0; kx < 4; ++kx)                                         \
            a[mi][kx] = *reinterpret_cast<const short8*>(gA + rowa + kx * 32 + q * 8); \
    }                                                                          \
    float4v acc[2][4];                                                         \
    _Pragma("unroll")                                                          \
    for (int mi = 0; mi < 2; ++mi)                                             \
        _Pragma("unroll")                                                      \
        for (int ni = 0; ni < 4; ++ni)                                         \
            acc[mi][ni] = (float4v){0.0f, 0.0f, 0.0f, 0.0f};                   \
    _Pragma("unroll")                                                          \
    for (int kx = 0; kx < 4; ++kx) {                                           \
        short8 bfr[4];                                                         \
        _Pragma("unroll")                                                      \
        for (int ni = 0; ni < 4; ++ni)                                         \
            bfr[ni] = *reinterpret_cast<const short8*>(                        \
                gB + (size_t)(v0 + ni * 16 + l16) * E_DIM + kx * 32 + q * 8);  \
        _Pragma("unroll")                                                      \
        for (int ni = 0; ni < 4; ++ni) {                                       \
            acc[0][ni] = __builtin_amdgcn_mfma_f32_16x16x32_bf16(a[0][kx], bfr[ni], acc[0][ni], 0, 0, 0); \
            acc[1][ni] = __builtin_amdgcn_mfma_f32_16x16x32_bf16(a[1][kx], bfr[ni], acc[1][ni], 0, 0, 0); \
        }                                                                      \
    }

// ---------------------------------------------------------------------------
// kp1: GEMM tile -> per-row (max, sumexp) partials. No logit store.
// ---------------------------------------------------------------------------
__global__ __launch_bounds__(256) void kp1(
        const __hip_bfloat16* __restrict__ xse,
        const __hip_bfloat16* __restrict__ e2vT,
        float* __restrict__ pmax,
        float* __restrict__ psum) {
    GEMM_REG_BODY(xse, e2vT)

#pragma unroll
    for (int mi = 0; mi < 2; ++mi) {
#pragma unroll
        for (int r = 0; r < 4; ++r) {
            float mx = -INFINITY;
#pragma unroll
            for (int ni = 0; ni < 4; ++ni) {
                const int col = v0 + ni * 16 + l16;
                const float x = (col < V_DIM) ? acc[mi][ni][r] : -INFINITY;
                mx = fmaxf(mx, x);
            }
            mx = fmaxf(mx, __shfl_xor(mx, 1));
            mx = fmaxf(mx, __shfl_xor(mx, 2));
            mx = fmaxf(mx, __shfl_xor(mx, 4));
            mx = fmaxf(mx, __shfl_xor(mx, 8));
            float s = 0.0f;
#pragma unroll
            for (int ni = 0; ni < 4; ++ni) {
                const int col = v0 + ni * 16 + l16;
                const float x = (col < V_DIM) ? acc[mi][ni][r] : -INFINITY;
                s += __expf(x - mx);  // exp(-inf) = 0 masks the tail
            }
            s += __shfl_xor(s, 1);
            s += __shfl_xor(s, 2);
            s += __shfl_xor(s, 4);
            s += __shfl_xor(s, 8);
            if (l16 == 0) {
                const int row = m0 + wm + mi * 16 + q * 4 + r;
                pmax[(size_t)row * NCT + vt] = mx;
                psum[(size_t)row * NCT + vt] = s;
            }
        }
    }
}

// ---------------------------------------------------------------------------
// kc: combine NCT partials per row -> stats[b] = logsumexp of the row
// ---------------------------------------------------------------------------
__global__ void kc_combine(const float* __restrict__ pmax,
                           const float* __restrict__ psum,
                           float* __restrict__ stats) {
    const int b = blockIdx.x;
    const int tid = threadIdx.x;
    float m = -INFINITY, s = 0.0f;
    for (int j = tid; j < NCT; j += 256) {
        const float mj = pmax[(size_t)b * NCT + j];
        const float sj = psum[(size_t)b * NCT + j];
        if (mj > m) { s = s * __expf(m - mj) + sj; m = mj; }
        else        { s += sj * __expf(mj - m); }
    }
    __shared__ float rm[256], rs[256];
    rm[tid] = m; rs[tid] = s;
    __syncthreads();
    for (int off = 128; off > 0; off >>= 1) {
        if (tid < off) {
            const float m2 = rm[tid + off], s2 = rs[tid + off];
            const float M = fmaxf(m, m2);
            s = s * __expf(m - M) + s2 * __expf(m2 - M);
            m = M;
            rm[tid] = m; rs[tid] = s;
        }
        __syncthreads();
    }
    if (tid == 0) stats[b] = m + __logf(s);
}

// ---------------------------------------------------------------------------
// kp2: recompute GEMM tile (bitwise-identical), subtract lse, store output.
// ---------------------------------------------------------------------------
__global__ __launch_bounds__(256) void kp2(
        const __hip_bfloat16* __restrict__ xse,
        const __hip_bfloat16* __restrict__ e2vT,
        const float* __restrict__ stats,
        float* __restrict__ out) {
    GEMM_REG_BODY(xse, e2vT)

#pragma unroll
    for (int mi = 0; mi < 2; ++mi) {
        const int rbase = m0 + wm + mi * 16 + q * 4;
        float l[4];
#pragma unroll
        for (int r = 0; r < 4; ++r) l[r] = stats[rbase + r];
#pragma unroll
        for (int ni = 0; ni < 4; ++ni) {
            const int col = v0 + ni * 16 + l16;
            if (col < V_DIM) {
#pragma unroll
                for (int r = 0; r < 4; ++r)
                    out[(size_t)(rbase + r) * V_DIM + col] = acc[mi][ni][r] - l[r];
            }
        }
    }
}

// ---------------------------------------------------------------------------
extern "C" void kernel_launch(void* const* d_in, const int* in_sizes, int n_in,
                              void* d_out, int out_size, void* d_ws, size_t ws_size,
                              hipStream_t stream) {
    const float* xs  = (const float*)d_in[0];
    // d_in[1] = metric (unused by forward)
    const float* EM  = (const float*)d_in[2];
    const float* e2v = (const float*)d_in[3];
    float* out = (float*)d_out;

    char* ws = (char*)d_ws;
    __hip_bfloat16* e2vT = (__hip_bfloat16*)ws;                         // 12,877,824 B
    size_t off = (size_t)V_PAD * E_DIM * 2;
    __hip_bfloat16* xse = (__hip_bfloat16*)(ws + off);                  // 262,144 B
    off += (size_t)B_ROWS * E_DIM * 2;
    float* pmax = (float*)(ws + off);                                   // 3,219,456 B
    off += (size_t)B_ROWS * NCT * 4;
    float* psum = (float*)(ws + off);                                   // 3,219,456 B
    off += (size_t)B_ROWS * NCT * 4;
    float* stats = (float*)(ws + off);                                  // 4,096 B

    hipLaunchKernelGGL(kfuse, dim3(B_ROWS + K0_BLOCKS), dim3(256), 0, stream,
                       xs, EM, xse, e2v, e2vT);
    hipLaunchKernelGGL(kp1, dim3(NCT, 8), dim3(256), 0, stream, xse, e2vT, pmax, psum);
    hipLaunchKernelGGL(kc_combine, dim3(B_ROWS), dim3(256), 0, stream, pmax, psum, stats);
    hipLaunchKernelGGL(kp2, dim3(NCT, 8), dim3(256), 0, stream, xse, e2vT, stats, out);
}